// Round 2
// baseline (228.590 us; speedup 1.0000x reference)
//
#include <hip/hip_runtime.h>
#include <hip/hip_bf16.h>

#define KT 32
#define START_TAG 30
#define END_TAG 31

__device__ __forceinline__ float exp2f_fast(float x) { return __builtin_amdgcn_exp2f(x); }
__device__ __forceinline__ float log2f_fast(float x) { return __builtin_amdgcn_logf(x); }  // v_log_f32 = log2

// One 64-lane wave per block handles TWO sequences (half h = lane>>5, tag k = lane&31).
// Prob-domain CRF forward: ahat[k] ~ exp(alpha[k]) * 2^-M. Per step:
//   s_k = sum_j E[k][j]*ahat[j]   (E row in 32 VGPRs, ahat via LDS broadcast reads)
//   ahat_new = s_k * Fc           (Fc = exp(feat_t[k]) * pending power-of-2 renorm)
// Renorm: every 4th step, scale 2^(127-e) with e = exponent(p[0]) captured the
// PREVIOUS iteration (off the critical path); M += e-127 (exact bookkeeping).
// Z = ln2*(M + log2(sum_k ahat*exp(trans[END][k]))).
__global__ __launch_bounds__(64) void crf_nll(
    const float* __restrict__ feats,   // [B,T,K] f32
    const float* __restrict__ trans,   // [K,K]   f32, trans[next][prev]
    const int*   __restrict__ tags,    // [B,T]
    const int*   __restrict__ masks,   // [B,T]
    float* __restrict__ out, int B, int T)
{
    constexpr float L2E = 1.4426950408889634f;
    constexpr float LN2 = 0.6931471805599453f;
    const int lane = threadIdx.x;
    const int k = lane & 31;
    const int h = lane >> 5;
    int b = blockIdx.x * 2 + h;
    const bool bvalid = (b < B);
    if (!bvalid) b = B - 1;   // clamp (store suppressed below)

    __shared__ float  Tl[KT * KT];   // natural-units transitions (gold lookups)
    __shared__ float4 p4[2][8];      // ahat row per half

    for (int i = lane; i < KT * KT; i += 64) Tl[i] = trans[i];

    // Per-lane row of E = exp(T). Row START is all zeros (INVALID -> exp2(-14427)=0).
    float E[KT];
#pragma unroll
    for (int j = 0; j < KT; ++j) E[j] = exp2f_fast(trans[k * KT + j] * L2E);
    const float E2 = exp2f_fast(trans[END_TAG * KT + k] * L2E);  // terminal row

    __syncthreads();

    const int*   tg = tags  + (size_t)b * T;
    const int*   mk = masks + (size_t)b * T;
    const float* fb = feats + (size_t)b * T * KT;

    // ---------- gold score + length (lanes of each half parallel over t) ----------
    float g = 0.f;
    int   Lp = 0;
    for (int c = 0; c < T; c += 32) {
        const int t  = c + k;
        const int mt = mk[t];
        Lp += mt;
        const int tagt  = tg[t];
        const int prev  = t ? tg[t - 1] : START_TAG;
        const int fprev = t ? mk[t - 1] : 1;
        if (mt)    g += fb[(size_t)t * KT + tagt];            // emission
        if (fprev) g += Tl[tagt * KT + prev];                 // transition prev->tagt
        if (t == T - 1 && mt) g += Tl[END_TAG * KT + tagt];   // END term iff full length
    }
#pragma unroll
    for (int d = 1; d < 32; d <<= 1) { g += __shfl_xor(g, d); Lp += __shfl_xor(Lp, d); }
    const int L    = Lp;                        // this half's length (>=1)
    const int Lmax = max(L, __shfl_xor(L, 32));

    // ---------- init DP ----------
    ((float*)p4)[lane] = (k == START_TAG) ? 1.f : 0.f;
    float ahat = (k == START_TAG) ? 1.f : 0.f;
    int M = 0;

    // feat pipeline depth 4: Fc (current, includes pending renorm), F1, raw v2, v3
    const int Tm1 = T - 1;
    float Fc = exp2f_fast(fb[k] * L2E);
    float F1 = exp2f_fast(fb[(size_t)min(1, Tm1) * KT + k] * L2E);
    float v2 = fb[(size_t)min(2, Tm1) * KT + k];
    float v3 = fb[(size_t)min(3, Tm1) * KT + k];
    int dM = 0;   // pending M increment, paired with the scale folded into Fc

    const int Lm4 = (Lmax + 3) & ~3;

#define STEP(TT, DO_RN, CAP_E) {                                              \
    float p[KT];                                                              \
    _Pragma("unroll")                                                         \
    for (int i = 0; i < 8; ++i) {                                             \
        const float4 q = p4[h][i];                                            \
        p[4*i+0] = q.x; p[4*i+1] = q.y; p[4*i+2] = q.z; p[4*i+3] = q.w;       \
    }                                                                         \
    int e_now = 127;                                                          \
    if (CAP_E) {                                                              \
        const unsigned pb = __float_as_uint(p[0]);                            \
        e_now = (int)((pb >> 23) & 255u);                                     \
        if (e_now < 1 || e_now > 253) e_now = 127;                            \
    }                                                                         \
    float a0 = 0.f, a1 = 0.f, a2 = 0.f, a3 = 0.f;                             \
    _Pragma("unroll")                                                         \
    for (int q8 = 0; q8 < 8; ++q8) {  /* last quad feeds all 4 accs */        \
        a0 = fmaf(E[4*q8+0], p[4*q8+0], a0);                                  \
        a1 = fmaf(E[4*q8+1], p[4*q8+1], a1);                                  \
        a2 = fmaf(E[4*q8+2], p[4*q8+2], a2);                                  \
        a3 = fmaf(E[4*q8+3], p[4*q8+3], a3);                                  \
    }                                                                         \
    const float val = ((a0 + a1) + (a2 + a3)) * Fc;                           \
    const bool act = (TT) < L;                                                \
    ahat = act ? val : ahat;                                                  \
    if (DO_RN) M += act ? dM : 0;                                             \
    ((float*)p4)[lane] = ahat;                                                \
    int tn = (TT) + 4; if (tn > Tm1) tn = Tm1;                                \
    const float vn = fb[(size_t)tn * KT + k];                                 \
    const float Fn = exp2f_fast(v2 * L2E);                                    \
    if (CAP_E) {                                                              \
        dM = e_now - 127;                                                     \
        Fc = F1 * __uint_as_float((unsigned)(254 - e_now) << 23);             \
    } else { Fc = F1; }                                                       \
    F1 = Fn; v2 = v3; v3 = vn;                                                \
}

    for (int t = 0; t < Lm4; t += 4) {
        STEP(t,     1, 0)
        STEP(t + 1, 0, 0)
        STEP(t + 2, 0, 0)
        STEP(t + 3, 0, 1)
    }
#undef STEP

    // terminal: Z = ln2 * (M + log2(sum_k ahat[k] * E2[k]))
    float term = ahat * E2;
#pragma unroll
    for (int d = 1; d < 32; d <<= 1) term += __shfl_xor(term, d);
    const float Z = ((float)M + log2f_fast(term)) * LN2;

    if (k == 0 && bvalid) out[b] = Z - g;
}

extern "C" void kernel_launch(void* const* d_in, const int* in_sizes, int n_in,
                              void* d_out, int out_size, void* d_ws, size_t ws_size,
                              hipStream_t stream) {
    const float* feats = (const float*)d_in[0];
    const float* trans = (const float*)d_in[1];
    const int*   tags  = (const int*)d_in[2];
    const int*   masks = (const int*)d_in[3];
    float* out = (float*)d_out;

    const int B = out_size;                 // 1024
    const int T = in_sizes[2] / B;          // 512
    const int blocks = (B + 1) / 2;         // 2 sequences per 64-thread block

    hipLaunchKernelGGL(crf_nll, dim3(blocks), dim3(64), 0, stream,
                       feats, trans, tags, masks, out, B, T);
}